// Round 14
// baseline (218.740 us; speedup 1.0000x reference)
//
#include <hip/hip_runtime.h>
#include <hip/hip_bf16.h>

#define NPTS 1048576
#define NCLS 20
#define GRIDC 512
#define TPB   32   // tiles (64 points) per block: 512*32*64 = NPTS

using bf16x8 = __attribute__((ext_vector_type(8))) short;
using f32x4  = __attribute__((ext_vector_type(4))) float;

__device__ inline short bft(float f) {
    unsigned u = __builtin_bit_cast(unsigned, f);
    u += 0x8000u;                  // round-to-nearest-ish (no NaN/inf in data)
    return (short)(u >> 16);
}

__device__ inline bf16x8 cvt8(float4 a, float4 b) {
    bf16x8 r;
    r[0]=bft(a.x); r[1]=bft(a.y); r[2]=bft(a.z); r[3]=bft(a.w);
    r[4]=bft(b.x); r[5]=bft(b.y); r[6]=bft(b.z); r[7]=bft(b.w);
    return r;
}

// ws layout (float offsets):
//   [0,4096)      stats: 32 slices x (sum[64] | sumsq[64])
//   [4096,4120)   loss acc: 8 slices x 3
//   [4120]        grid barrier counter (int)
//   [8192,10240)  w1f   (4096 shorts)
//   [10240,11264) wsegf (2048 shorts)

// ---- init + prep (12 blocks): zero accumulators + barrier, build MFMA B-frag layouts
__global__ void init_prep_kernel(const float* __restrict__ w1, const float* __restrict__ wseg,
                                 float* __restrict__ ws) {
    int b = blockIdx.x, t = threadIdx.x;
    short* w1f   = (short*)(ws + 8192);
    short* wsegf = (short*)(ws + 10240);
    if (b == 0) for (int i = t; i < 4288; i += 256) ws[i] = 0.f;
    if (b < 8) {
        if (t < 64) {
            int g = b*64 + t;
            int lane = g & 63, ksb = g >> 6;
            int cb = ksb >> 1, ks = ksb & 1;
            int c = cb*16 + (lane & 15);
            int kb = ks*32 + (lane >> 4)*8;
            for (int j = 0; j < 8; ++j) w1f[g*8+j] = bft(w1[(kb+j)*64 + c]);
        }
    } else {
        if (t < 64) {
            int g = (b-8)*64 + t;
            int lane = g & 63, ksb = g >> 6;
            int cb = ksb >> 1, ks = ksb & 1;
            int c = cb*16 + (lane & 15);
            int kb = ks*32 + (lane >> 4)*8;
            for (int j = 0; j < 8; ++j)
                wsegf[g*8+j] = (c < NCLS) ? bft(wseg[(kb+j)*NCLS + c]) : (short)0;
        }
    }
}

#define SEL4(v0,v1,v2,v3) (l15==0 ? (v0) : (l15==1 ? (v1) : (l15==2 ? (v2) : (v3))))
#define SEL3(v0,v1,v2)    (l15==0 ? (v0) : (l15==1 ? (v1) : (v2)))

// ---- mega kernel: pass1 (logits+stats) -> grid spin-barrier -> finstats -> pass2 (bias+loss)
__global__ __launch_bounds__(256) void mega_kernel(
    const float* __restrict__ feat, const float* __restrict__ b1, const float* __restrict__ bseg,
    const short* __restrict__ w1f, const short* __restrict__ wsegf,
    const float* __restrict__ gamma, const float* __restrict__ beta,
    const float* __restrict__ w2, const float* __restrict__ b2,
    const float* __restrict__ coord, const float* __restrict__ bottom,
    const float* __restrict__ stemv, const int* __restrict__ inst,
    float* __restrict__ out_logits, float* __restrict__ out_bias,
    float* __restrict__ stats, float* __restrict__ lossacc, int* __restrict__ bar) {

    const int tid  = threadIdx.x;
    const int wave = tid >> 6;
    const int lane = tid & 63;
    const int l15  = lane & 15;
    const int lk   = lane >> 4;

    __shared__ float lgl[4][320];   // per-wave logits tile: 16 points x 20 ch
    __shared__ float red[4][128];
    __shared__ float psum[4][64], psq[4][64], abls[128];
    __shared__ float sred[3][4];

    // ---- weight fragments (shared by both phases)
    bf16x8 w1frag[4][2];
    #pragma unroll
    for (int cb = 0; cb < 4; ++cb)
        #pragma unroll
        for (int ks = 0; ks < 2; ++ks)
            w1frag[cb][ks] = *(const bf16x8*)&w1f[((cb*2+ks)*64 + lane)*8];
    bf16x8 wsfrag[2][2];
    #pragma unroll
    for (int cb = 0; cb < 2; ++cb)
        #pragma unroll
        for (int ks = 0; ks < 2; ++ks)
            wsfrag[cb][ks] = *(const bf16x8*)&wsegf[((cb*2+ks)*64 + lane)*8];

    float b1v[4];
    #pragma unroll
    for (int cb = 0; cb < 4; ++cb) b1v[cb] = b1[cb*16 + l15];
    float bsegv[2];
    #pragma unroll
    for (int cb = 0; cb < 2; ++cb) { int c = cb*16+l15; bsegv[cb] = (c < NCLS) ? bseg[c] : 0.f; }

    const float* src = feat + ((size_t)blockIdx.x * TPB * 64 + wave*16 + l15) * 64 + lk*8;

    // ================= PHASE 1: logits + stats =================
    {
        float ssum[4] = {0,0,0,0}, ssq[4] = {0,0,0,0};

        auto do_tile = [&](float4 q0, float4 q1, float4 q2, float4 q3, int tt) {
            bf16x8 a0 = cvt8(q0, q1);
            bf16x8 a1 = cvt8(q2, q3);
            const int p0 = (blockIdx.x * TPB + tt) * 64 + wave * 16;

            f32x4 acc[4];
            #pragma unroll
            for (int cb = 0; cb < 4; ++cb) { acc[cb][0]=b1v[cb]; acc[cb][1]=b1v[cb]; acc[cb][2]=b1v[cb]; acc[cb][3]=b1v[cb]; }
            #pragma unroll
            for (int cb = 0; cb < 4; ++cb) {
                acc[cb] = __builtin_amdgcn_mfma_f32_16x16x32_bf16(a0, w1frag[cb][0], acc[cb], 0, 0, 0);
                acc[cb] = __builtin_amdgcn_mfma_f32_16x16x32_bf16(a1, w1frag[cb][1], acc[cb], 0, 0, 0);
            }
            #pragma unroll
            for (int cb = 0; cb < 4; ++cb)
                #pragma unroll
                for (int i = 0; i < 4; ++i) { float h = acc[cb][i]; ssum[cb] += h; ssq[cb] += h*h; }

            f32x4 lacc2[2];
            #pragma unroll
            for (int cb = 0; cb < 2; ++cb) { lacc2[cb][0]=0; lacc2[cb][1]=0; lacc2[cb][2]=0; lacc2[cb][3]=0; }
            #pragma unroll
            for (int cb = 0; cb < 2; ++cb) {
                lacc2[cb] = __builtin_amdgcn_mfma_f32_16x16x32_bf16(a0, wsfrag[cb][0], lacc2[cb], 0, 0, 0);
                lacc2[cb] = __builtin_amdgcn_mfma_f32_16x16x32_bf16(a1, wsfrag[cb][1], lacc2[cb], 0, 0, 0);
            }
            #pragma unroll
            for (int i = 0; i < 4; ++i)
                lgl[wave][(lk*4+i)*NCLS + l15] = lacc2[0][i] + bsegv[0];
            if (l15 < 4) {
                #pragma unroll
                for (int i = 0; i < 4; ++i)
                    lgl[wave][(lk*4+i)*NCLS + 16 + l15] = lacc2[1][i] + bsegv[1];
            }
            float* gbase = out_logits + (size_t)p0 * NCLS;
            f32x4 v0 = *(const f32x4*)&lgl[wave][lane*4];
            __builtin_nontemporal_store(v0, (f32x4*)(gbase + lane*4));
            if (lane < 16) {
                f32x4 v1 = *(const f32x4*)&lgl[wave][256 + lane*4];
                __builtin_nontemporal_store(v1, (f32x4*)(gbase + 256 + lane*4));
            }
        };

        float4 r0 = *(const float4*)src,          r1 = *(const float4*)(src + 4);
        float4 r2 = *(const float4*)(src + 32),   r3 = *(const float4*)(src + 36);
        float4 r4 = *(const float4*)(src + 4096), r5 = *(const float4*)(src + 4100);
        float4 r6 = *(const float4*)(src + 4128), r7 = *(const float4*)(src + 4132);

        for (int p = 0; p < TPB/2; ++p) {
            float4 n0=r0,n1=r1,n2=r2,n3=r3,n4=r4,n5=r5,n6=r6,n7=r7;
            if (p + 1 < TPB/2) {
                const float* sn = src + (size_t)(2*p + 2) * 4096;
                n0 = *(const float4*)sn;          n1 = *(const float4*)(sn + 4);
                n2 = *(const float4*)(sn + 32);   n3 = *(const float4*)(sn + 36);
                n4 = *(const float4*)(sn + 4096); n5 = *(const float4*)(sn + 4100);
                n6 = *(const float4*)(sn + 4128); n7 = *(const float4*)(sn + 4132);
            }
            do_tile(r0, r1, r2, r3, 2*p);
            do_tile(r4, r5, r6, r7, 2*p + 1);
            r0=n0; r1=n1; r2=n2; r3=n3; r4=n4; r5=n5; r6=n6; r7=n7;
        }

        #pragma unroll
        for (int cb = 0; cb < 4; ++cb) {
            ssum[cb] += __shfl_xor(ssum[cb], 16); ssum[cb] += __shfl_xor(ssum[cb], 32);
            ssq[cb]  += __shfl_xor(ssq[cb], 16);  ssq[cb]  += __shfl_xor(ssq[cb], 32);
        }
        if (lk == 0) {
            #pragma unroll
            for (int cb = 0; cb < 4; ++cb) {
                red[wave][cb*16 + l15]      = ssum[cb];
                red[wave][64 + cb*16 + l15] = ssq[cb];
            }
        }
        __syncthreads();
        if (tid < 128) {
            float v = red[0][tid] + red[1][tid] + red[2][tid] + red[3][tid];
            atomicAdd(&stats[(blockIdx.x & 31) * 128 + tid], v);
        }
    }

    // ================= GRID BARRIER (all 512 blocks co-resident: 2/CU) =================
    __syncthreads();
    if (tid == 0) {
        __threadfence();
        atomicAdd(bar, 1);
        while (__hip_atomic_load(bar, __ATOMIC_ACQUIRE, __HIP_MEMORY_SCOPE_AGENT) < GRIDC)
            __builtin_amdgcn_s_sleep(2);
    }
    __syncthreads();

    // ================= inline finstats (AGENT-scope loads bypass stale caches) ==========
    {
        int c = tid & 63, part = tid >> 6;
        float s = 0.f, q = 0.f;
        #pragma unroll
        for (int sl = part*8; sl < part*8 + 8; ++sl) {
            s += __hip_atomic_load(&stats[sl*128 + c],      __ATOMIC_RELAXED, __HIP_MEMORY_SCOPE_AGENT);
            q += __hip_atomic_load(&stats[sl*128 + 64 + c], __ATOMIC_RELAXED, __HIP_MEMORY_SCOPE_AGENT);
        }
        psum[part][c] = s; psq[part][c] = q;
    }
    __syncthreads();
    if (tid < 64) {
        float ss = psum[0][tid] + psum[1][tid] + psum[2][tid] + psum[3][tid];
        float qq = psq[0][tid] + psq[1][tid] + psq[2][tid] + psq[3][tid];
        float mu  = ss * (1.0f / NPTS);
        float var = qq * (1.0f / NPTS) - mu * mu;
        float a = gamma[tid] * rsqrtf(var + 1e-3f);
        abls[tid] = a;
        abls[64 + tid] = beta[tid] - mu * a;
    }
    __syncthreads();

    // ================= PHASE 2: bias + fused loss =================
    {
        float av[4], bsv[4], w2v[4][3];
        #pragma unroll
        for (int cb = 0; cb < 4; ++cb) {
            int c = cb*16 + l15;
            av[cb]  = abls[c];
            bsv[cb] = abls[64 + c];
            #pragma unroll
            for (int j = 0; j < 3; ++j) w2v[cb][j] = w2[c*3 + j];
        }
        float b2v = (l15 < 3) ? b2[l15] : 0.f;
        float b2x = b2[0], b2y = b2[1], b2z = b2[2];

        float am = 0.f, al = 0.f, ac = 0.f;

        auto do_tile = [&](float4 q0, float4 q1, float4 q2, float4 q3, int tt) {
            bf16x8 a0 = cvt8(q0, q1);
            bf16x8 a1 = cvt8(q2, q3);
            const int p0 = (blockIdx.x * TPB + tt) * 64 + wave * 16;

            f32x4 acc[4];
            #pragma unroll
            for (int cb = 0; cb < 4; ++cb) { acc[cb][0]=b1v[cb]; acc[cb][1]=b1v[cb]; acc[cb][2]=b1v[cb]; acc[cb][3]=b1v[cb]; }
            #pragma unroll
            for (int cb = 0; cb < 4; ++cb) {
                acc[cb] = __builtin_amdgcn_mfma_f32_16x16x32_bf16(a0, w1frag[cb][0], acc[cb], 0, 0, 0);
                acc[cb] = __builtin_amdgcn_mfma_f32_16x16x32_bf16(a1, w1frag[cb][1], acc[cb], 0, 0, 0);
            }

            float pb[4][3];
            #pragma unroll
            for (int i = 0; i < 4; ++i) { pb[i][0]=0; pb[i][1]=0; pb[i][2]=0; }
            #pragma unroll
            for (int cb = 0; cb < 4; ++cb)
                #pragma unroll
                for (int i = 0; i < 4; ++i) {
                    float hn = fmaxf(acc[cb][i] * av[cb] + bsv[cb], 0.f);
                    #pragma unroll
                    for (int j = 0; j < 3; ++j) pb[i][j] += hn * w2v[cb][j];
                }
            #pragma unroll
            for (int m = 1; m <= 8; m <<= 1)
                #pragma unroll
                for (int i = 0; i < 4; ++i) {
                    pb[i][0] += __shfl_xor(pb[i][0], m);
                    pb[i][1] += __shfl_xor(pb[i][1], m);
                    pb[i][2] += __shfl_xor(pb[i][2], m);
                }
            if (l15 < 3) {
                #pragma unroll
                for (int i = 0; i < 4; ++i) {
                    float v = SEL3(pb[i][0], pb[i][1], pb[i][2]) + b2v;
                    out_bias[(size_t)(p0 + lk*4 + i) * 3 + l15] = v;
                }
            }
            if (l15 < 4) {
                int p = p0 + lk*4 + l15;
                float px = SEL4(pb[0][0], pb[1][0], pb[2][0], pb[3][0]) + b2x;
                float py = SEL4(pb[0][1], pb[1][1], pb[2][1], pb[3][1]) + b2y;
                float pz = SEL4(pb[0][2], pb[1][2], pb[2][2], pb[3][2]) + b2z;
                float m  = (inst[p] != -1) ? 1.f : 0.f;
                float cx = coord[p*3+0],  cy = coord[p*3+1],  cz = coord[p*3+2];
                float bx = bottom[p*3+0], by = bottom[p*3+1], bz = bottom[p*3+2];
                float vx = stemv[p*3+0],  vy = stemv[p*3+1],  vz = stemv[p*3+2];
                float dx = cx - bx, dy = cy - by, dz = cz - bz;
                float proj = dx*vx + dy*vy + dz*vz;
                float gx = proj*vx - dx, gy = proj*vy - dy, gz = proj*vz - dz;
                float l1 = fabsf(px-gx) + fabsf(py-gy) + fabsf(pz-gz);
                float nb = sqrtf(px*px + py*py + pz*pz) + 1e-8f;
                float ng = sqrtf(gx*gx + gy*gy + gz*gz) + 1e-8f;
                float cs = -(px*gx + py*gy + pz*gz) / (nb * ng);
                am += m; al += l1 * m; ac += cs * m;
            }
        };

        float4 r0 = *(const float4*)src,          r1 = *(const float4*)(src + 4);
        float4 r2 = *(const float4*)(src + 32),   r3 = *(const float4*)(src + 36);
        float4 r4 = *(const float4*)(src + 4096), r5 = *(const float4*)(src + 4100);
        float4 r6 = *(const float4*)(src + 4128), r7 = *(const float4*)(src + 4132);

        for (int p = 0; p < TPB/2; ++p) {
            float4 n0=r0,n1=r1,n2=r2,n3=r3,n4=r4,n5=r5,n6=r6,n7=r7;
            if (p + 1 < TPB/2) {
                const float* sn = src + (size_t)(2*p + 2) * 4096;
                n0 = *(const float4*)sn;          n1 = *(const float4*)(sn + 4);
                n2 = *(const float4*)(sn + 32);   n3 = *(const float4*)(sn + 36);
                n4 = *(const float4*)(sn + 4096); n5 = *(const float4*)(sn + 4100);
                n6 = *(const float4*)(sn + 4128); n7 = *(const float4*)(sn + 4132);
            }
            do_tile(r0, r1, r2, r3, 2*p);
            do_tile(r4, r5, r6, r7, 2*p + 1);
            r0=n0; r1=n1; r2=n2; r3=n3; r4=n4; r5=n5; r6=n6; r7=n7;
        }

        #pragma unroll
        for (int m2 = 1; m2 < 64; m2 <<= 1) {
            am += __shfl_xor(am, m2); al += __shfl_xor(al, m2); ac += __shfl_xor(ac, m2);
        }
        if (lane == 0) { sred[0][wave] = am; sred[1][wave] = al; sred[2][wave] = ac; }
        __syncthreads();
        if (tid == 0) {
            float* a = &lossacc[(blockIdx.x & 7) * 3];
            atomicAdd(&a[0], sred[0][0]+sred[0][1]+sred[0][2]+sred[0][3]);
            atomicAdd(&a[1], sred[1][0]+sred[1][1]+sred[1][2]+sred[1][3]);
            atomicAdd(&a[2], sred[2][0]+sred[2][1]+sred[2][2]+sred[2][3]);
        }
    }
}

__global__ void finloss_kernel(const float* __restrict__ lacc, float* __restrict__ out) {
    float m = 0.f, l = 0.f, c = 0.f;
    #pragma unroll
    for (int sl = 0; sl < 8; ++sl) { m += lacc[sl*3+0]; l += lacc[sl*3+1]; c += lacc[sl*3+2]; }
    out[0] = (l + c) / (m + 1e-8f);
}

extern "C" void kernel_launch(void* const* d_in, const int* in_sizes, int n_in,
                              void* d_out, int out_size, void* d_ws, size_t ws_size,
                              hipStream_t stream) {
    const float* coord  = (const float*)d_in[0];
    const float* feat   = (const float*)d_in[1];
    const float* bottom = (const float*)d_in[2];
    const float* stemv  = (const float*)d_in[3];
    const int*   inst   = (const int*)d_in[4];
    const float* w1     = (const float*)d_in[5];
    const float* b1     = (const float*)d_in[6];
    const float* gamma  = (const float*)d_in[7];
    const float* beta   = (const float*)d_in[8];
    const float* w2     = (const float*)d_in[9];
    const float* b2     = (const float*)d_in[10];
    const float* wseg   = (const float*)d_in[11];
    const float* bseg   = (const float*)d_in[12];

    float* out    = (float*)d_out;
    float* logits = out;
    float* bias   = out + (size_t)NPTS * NCLS;
    float* lossp  = out + (size_t)NPTS * 23;

    float* ws    = (float*)d_ws;
    float* stats = ws;                    // [32][128]
    float* lacc  = ws + 4096;             // [8][3]
    int*   bar   = (int*)(ws + 4120);     // grid barrier counter
    short* w1f   = (short*)(ws + 8192);   // 4096 bf16
    short* wsegf = (short*)(ws + 10240);  // 2048 bf16

    init_prep_kernel<<<12, 256, 0, stream>>>(w1, wseg, ws);
    mega_kernel<<<GRIDC, 256, 0, stream>>>(feat, b1, bseg, w1f, wsegf, gamma, beta, w2, b2,
                                           coord, bottom, stemv, inst,
                                           logits, bias, stats, lacc, bar);
    finloss_kernel<<<1, 1, 0, stream>>>(lacc, lossp);
}

// Round 15
// 176.830 us; speedup vs baseline: 1.2370x; 1.2370x over previous
//
#include <hip/hip_runtime.h>
#include <hip/hip_bf16.h>

#define NPTS 1048576
#define NCLS 20
#define TILES 8
#define GRID  2048

using bf16x8 = __attribute__((ext_vector_type(8))) short;
using f32x4  = __attribute__((ext_vector_type(4))) float;

#define SB() __builtin_amdgcn_sched_barrier(0)

__device__ inline short bft(float f) {
    unsigned u = __builtin_bit_cast(unsigned, f);
    u += 0x8000u;                  // round-to-nearest-ish (no NaN/inf in data)
    return (short)(u >> 16);
}

__device__ inline bf16x8 cvt8(float4 a, float4 b) {
    bf16x8 r;
    r[0]=bft(a.x); r[1]=bft(a.y); r[2]=bft(a.z); r[3]=bft(a.w);
    r[4]=bft(b.x); r[5]=bft(b.y); r[6]=bft(b.z); r[7]=bft(b.w);
    return r;
}

// depth-4 register pipeline (named buffers, fully static)
#define LOAD4(P, off) \
    P##0 = *(const float4*)(src + (off));      P##1 = *(const float4*)(src + (off) + 4); \
    P##2 = *(const float4*)(src + (off) + 32); P##3 = *(const float4*)(src + (off) + 36);

// ws layout (float offsets):
//   [0,4096)      stats: 32 slices x (sum[64] | sumsq[64])
//   [4096,4120)   loss acc: 8 slices x 3
//   [4160,4288)   ab: scale[64] | shift[64]
//   [8192,10240)  w1f   (4096 shorts)
//   [10240,11264) wsegf (2048 shorts)

// ---- init + prep (12 blocks)
__global__ void init_prep_kernel(const float* __restrict__ w1, const float* __restrict__ wseg,
                                 float* __restrict__ ws) {
    int b = blockIdx.x, t = threadIdx.x;
    short* w1f   = (short*)(ws + 8192);
    short* wsegf = (short*)(ws + 10240);
    if (b == 0) for (int i = t; i < 4288; i += 256) ws[i] = 0.f;
    if (b < 8) {
        if (t < 64) {
            int g = b*64 + t;
            int lane = g & 63, ksb = g >> 6;
            int cb = ksb >> 1, ks = ksb & 1;
            int c = cb*16 + (lane & 15);
            int kb = ks*32 + (lane >> 4)*8;
            for (int j = 0; j < 8; ++j) w1f[g*8+j] = bft(w1[(kb+j)*64 + c]);
        }
    } else {
        if (t < 64) {
            int g = (b-8)*64 + t;
            int lane = g & 63, ksb = g >> 6;
            int cb = ksb >> 1, ks = ksb & 1;
            int c = cb*16 + (lane & 15);
            int kb = ks*32 + (lane >> 4)*8;
            for (int j = 0; j < 8; ++j)
                wsegf[g*8+j] = (c < NCLS) ? bft(wseg[(kb+j)*NCLS + c]) : (short)0;
        }
    }
}

// ---- pass1: h = feat@w1+b1 -> per-channel sum/sumsq; logits = feat@wseg+bseg
__global__ __launch_bounds__(256) void pass1_kernel(
    const float* __restrict__ feat, const float* __restrict__ b1, const float* __restrict__ bseg,
    const short* __restrict__ w1f, const short* __restrict__ wsegf,
    float* __restrict__ out_logits, float* __restrict__ stats) {

    const int tid  = threadIdx.x;
    const int wave = tid >> 6;
    const int lane = tid & 63;
    const int l15  = lane & 15;
    const int lk   = lane >> 4;

    __shared__ float lgl[4][320];   // per-wave logits tile: 16 points x 20 ch

    bf16x8 w1frag[4][2];
    #pragma unroll
    for (int cb = 0; cb < 4; ++cb)
        #pragma unroll
        for (int ks = 0; ks < 2; ++ks)
            w1frag[cb][ks] = *(const bf16x8*)&w1f[((cb*2+ks)*64 + lane)*8];
    bf16x8 wsfrag[2][2];
    #pragma unroll
    for (int cb = 0; cb < 2; ++cb)
        #pragma unroll
        for (int ks = 0; ks < 2; ++ks)
            wsfrag[cb][ks] = *(const bf16x8*)&wsegf[((cb*2+ks)*64 + lane)*8];

    float b1v[4];
    #pragma unroll
    for (int cb = 0; cb < 4; ++cb) b1v[cb] = b1[cb*16 + l15];
    float bsegv[2];
    #pragma unroll
    for (int cb = 0; cb < 2; ++cb) { int c = cb*16+l15; bsegv[cb] = (c < NCLS) ? bseg[c] : 0.f; }

    float ssum[4] = {0,0,0,0}, ssq[4] = {0,0,0,0};

    auto do_tile = [&](float4 q0, float4 q1, float4 q2, float4 q3, int tt) {
        bf16x8 a0 = cvt8(q0, q1);
        bf16x8 a1 = cvt8(q2, q3);
        const int p0 = (blockIdx.x * TILES + tt) * 64 + wave * 16;

        f32x4 acc[4];
        #pragma unroll
        for (int cb = 0; cb < 4; ++cb) { acc[cb][0]=b1v[cb]; acc[cb][1]=b1v[cb]; acc[cb][2]=b1v[cb]; acc[cb][3]=b1v[cb]; }
        #pragma unroll
        for (int cb = 0; cb < 4; ++cb) {
            acc[cb] = __builtin_amdgcn_mfma_f32_16x16x32_bf16(a0, w1frag[cb][0], acc[cb], 0, 0, 0);
            acc[cb] = __builtin_amdgcn_mfma_f32_16x16x32_bf16(a1, w1frag[cb][1], acc[cb], 0, 0, 0);
        }
        #pragma unroll
        for (int cb = 0; cb < 4; ++cb)
            #pragma unroll
            for (int i = 0; i < 4; ++i) { float h = acc[cb][i]; ssum[cb] += h; ssq[cb] += h*h; }

        f32x4 lacc[2];
        #pragma unroll
        for (int cb = 0; cb < 2; ++cb) { lacc[cb][0]=0; lacc[cb][1]=0; lacc[cb][2]=0; lacc[cb][3]=0; }
        #pragma unroll
        for (int cb = 0; cb < 2; ++cb) {
            lacc[cb] = __builtin_amdgcn_mfma_f32_16x16x32_bf16(a0, wsfrag[cb][0], lacc[cb], 0, 0, 0);
            lacc[cb] = __builtin_amdgcn_mfma_f32_16x16x32_bf16(a1, wsfrag[cb][1], lacc[cb], 0, 0, 0);
        }
        #pragma unroll
        for (int i = 0; i < 4; ++i)
            lgl[wave][(lk*4+i)*NCLS + l15] = lacc[0][i] + bsegv[0];
        if (l15 < 4) {
            #pragma unroll
            for (int i = 0; i < 4; ++i)
                lgl[wave][(lk*4+i)*NCLS + 16 + l15] = lacc[1][i] + bsegv[1];
        }
        float* gbase = out_logits + (size_t)p0 * NCLS;
        f32x4 v0 = *(const f32x4*)&lgl[wave][lane*4];
        __builtin_nontemporal_store(v0, (f32x4*)(gbase + lane*4));
        if (lane < 16) {
            f32x4 v1 = *(const f32x4*)&lgl[wave][256 + lane*4];
            __builtin_nontemporal_store(v1, (f32x4*)(gbase + 256 + lane*4));
        }
    };

    const float* src = feat + ((size_t)blockIdx.x * TILES * 64 + wave*16 + l15) * 64 + lk*8;
    float4 A0,A1,A2,A3, B0,B1,B2,B3, C0,C1,C2,C3, D0,D1,D2,D3;
    LOAD4(A, 0); LOAD4(B, 4096); LOAD4(C, 8192); LOAD4(D, 12288);
    SB();
    do_tile(A0,A1,A2,A3, 0); LOAD4(A, 16384); SB();
    do_tile(B0,B1,B2,B3, 1); LOAD4(B, 20480); SB();
    do_tile(C0,C1,C2,C3, 2); LOAD4(C, 24576); SB();
    do_tile(D0,D1,D2,D3, 3); LOAD4(D, 28672); SB();
    do_tile(A0,A1,A2,A3, 4);
    do_tile(B0,B1,B2,B3, 5);
    do_tile(C0,C1,C2,C3, 6);
    do_tile(D0,D1,D2,D3, 7);

    #pragma unroll
    for (int cb = 0; cb < 4; ++cb) {
        ssum[cb] += __shfl_xor(ssum[cb], 16); ssum[cb] += __shfl_xor(ssum[cb], 32);
        ssq[cb]  += __shfl_xor(ssq[cb], 16);  ssq[cb]  += __shfl_xor(ssq[cb], 32);
    }
    __shared__ float red[4][128];
    if (lk == 0) {
        #pragma unroll
        for (int cb = 0; cb < 4; ++cb) {
            red[wave][cb*16 + l15]      = ssum[cb];
            red[wave][64 + cb*16 + l15] = ssq[cb];
        }
    }
    __syncthreads();
    if (tid < 128) {
        float v = red[0][tid] + red[1][tid] + red[2][tid] + red[3][tid];
        atomicAdd(&stats[(blockIdx.x & 31) * 128 + tid], v);
    }
}

// ---- finalize BN stats -> per-channel scale/shift
__global__ void finstats_kernel(const float* __restrict__ stats, const float* __restrict__ gamma,
                                const float* __restrict__ beta, float* __restrict__ ab) {
    int c = threadIdx.x;  // 64
    float s = 0.f, q = 0.f;
    #pragma unroll
    for (int sl = 0; sl < 32; ++sl) { s += stats[sl*128 + c]; q += stats[sl*128 + 64 + c]; }
    float mu  = s * (1.0f / NPTS);
    float var = q * (1.0f / NPTS) - mu * mu;
    float a = gamma[c] * rsqrtf(var + 1e-3f);
    ab[c] = a;
    ab[64 + c] = beta[c] - mu * a;
}

#define SEL4(v0,v1,v2,v3) (l15==0 ? (v0) : (l15==1 ? (v1) : (l15==2 ? (v2) : (v3))))
#define SEL3(v0,v1,v2)    (l15==0 ? (v0) : (l15==1 ? (v1) : (v2)))

// ---- pass2 (+fused loss): recompute h, BN+ReLU, bias_pred = hn@w2 + b2; loss terms
__global__ __launch_bounds__(256) void pass2_kernel(
    const float* __restrict__ feat, const float* __restrict__ b1,
    const short* __restrict__ w1f, const float* __restrict__ ab,
    const float* __restrict__ w2, const float* __restrict__ b2,
    const float* __restrict__ coord, const float* __restrict__ bottom,
    const float* __restrict__ stemv, const int* __restrict__ inst,
    float* __restrict__ out_bias, float* __restrict__ lossacc) {

    const int tid  = threadIdx.x;
    const int wave = tid >> 6;
    const int lane = tid & 63;
    const int l15  = lane & 15;
    const int lk   = lane >> 4;

    bf16x8 w1frag[4][2];
    #pragma unroll
    for (int cb = 0; cb < 4; ++cb)
        #pragma unroll
        for (int ks = 0; ks < 2; ++ks)
            w1frag[cb][ks] = *(const bf16x8*)&w1f[((cb*2+ks)*64 + lane)*8];

    float b1v[4], av[4], bsv[4], w2v[4][3];
    #pragma unroll
    for (int cb = 0; cb < 4; ++cb) {
        int c = cb*16 + l15;
        b1v[cb] = b1[c];
        av[cb]  = ab[c];
        bsv[cb] = ab[64 + c];
        #pragma unroll
        for (int j = 0; j < 3; ++j) w2v[cb][j] = w2[c*3 + j];
    }
    float b2v = (l15 < 3) ? b2[l15] : 0.f;
    float b2x = b2[0], b2y = b2[1], b2z = b2[2];

    float am = 0.f, al = 0.f, ac = 0.f;   // loss accumulators

    auto do_tile = [&](float4 q0, float4 q1, float4 q2, float4 q3, int tt) {
        bf16x8 a0 = cvt8(q0, q1);
        bf16x8 a1 = cvt8(q2, q3);
        const int p0 = (blockIdx.x * TILES + tt) * 64 + wave * 16;

        f32x4 acc[4];
        #pragma unroll
        for (int cb = 0; cb < 4; ++cb) { acc[cb][0]=b1v[cb]; acc[cb][1]=b1v[cb]; acc[cb][2]=b1v[cb]; acc[cb][3]=b1v[cb]; }
        #pragma unroll
        for (int cb = 0; cb < 4; ++cb) {
            acc[cb] = __builtin_amdgcn_mfma_f32_16x16x32_bf16(a0, w1frag[cb][0], acc[cb], 0, 0, 0);
            acc[cb] = __builtin_amdgcn_mfma_f32_16x16x32_bf16(a1, w1frag[cb][1], acc[cb], 0, 0, 0);
        }

        float pb[4][3];
        #pragma unroll
        for (int i = 0; i < 4; ++i) { pb[i][0]=0; pb[i][1]=0; pb[i][2]=0; }
        #pragma unroll
        for (int cb = 0; cb < 4; ++cb)
            #pragma unroll
            for (int i = 0; i < 4; ++i) {
                float hn = fmaxf(acc[cb][i] * av[cb] + bsv[cb], 0.f);
                #pragma unroll
                for (int j = 0; j < 3; ++j) pb[i][j] += hn * w2v[cb][j];
            }
        #pragma unroll
        for (int m = 1; m <= 8; m <<= 1)
            #pragma unroll
            for (int i = 0; i < 4; ++i) {
                pb[i][0] += __shfl_xor(pb[i][0], m);
                pb[i][1] += __shfl_xor(pb[i][1], m);
                pb[i][2] += __shfl_xor(pb[i][2], m);
            }
        if (l15 < 3) {
            #pragma unroll
            for (int i = 0; i < 4; ++i) {
                float v = SEL3(pb[i][0], pb[i][1], pb[i][2]) + b2v;
                out_bias[(size_t)(p0 + lk*4 + i) * 3 + l15] = v;
            }
        }
        if (l15 < 4) {
            int p = p0 + lk*4 + l15;
            float px = SEL4(pb[0][0], pb[1][0], pb[2][0], pb[3][0]) + b2x;
            float py = SEL4(pb[0][1], pb[1][1], pb[2][1], pb[3][1]) + b2y;
            float pz = SEL4(pb[0][2], pb[1][2], pb[2][2], pb[3][2]) + b2z;
            float m  = (inst[p] != -1) ? 1.f : 0.f;
            float cx = coord[p*3+0],  cy = coord[p*3+1],  cz = coord[p*3+2];
            float bx = bottom[p*3+0], by = bottom[p*3+1], bz = bottom[p*3+2];
            float vx = stemv[p*3+0],  vy = stemv[p*3+1],  vz = stemv[p*3+2];
            float dx = cx - bx, dy = cy - by, dz = cz - bz;
            float proj = dx*vx + dy*vy + dz*vz;
            float gx = proj*vx - dx, gy = proj*vy - dy, gz = proj*vz - dz;
            float l1 = fabsf(px-gx) + fabsf(py-gy) + fabsf(pz-gz);
            float nb = sqrtf(px*px + py*py + pz*pz) + 1e-8f;
            float ng = sqrtf(gx*gx + gy*gy + gz*gz) + 1e-8f;
            float cs = -(px*gx + py*gy + pz*gz) / (nb * ng);
            am += m; al += l1 * m; ac += cs * m;
        }
    };

    const float* src = feat + ((size_t)blockIdx.x * TILES * 64 + wave*16 + l15) * 64 + lk*8;
    float4 A0,A1,A2,A3, B0,B1,B2,B3, C0,C1,C2,C3, D0,D1,D2,D3;
    LOAD4(A, 0); LOAD4(B, 4096); LOAD4(C, 8192); LOAD4(D, 12288);
    SB();
    do_tile(A0,A1,A2,A3, 0); LOAD4(A, 16384); SB();
    do_tile(B0,B1,B2,B3, 1); LOAD4(B, 20480); SB();
    do_tile(C0,C1,C2,C3, 2); LOAD4(C, 24576); SB();
    do_tile(D0,D1,D2,D3, 3); LOAD4(D, 28672); SB();
    do_tile(A0,A1,A2,A3, 4);
    do_tile(B0,B1,B2,B3, 5);
    do_tile(C0,C1,C2,C3, 6);
    do_tile(D0,D1,D2,D3, 7);

    // block-level loss reduction
    #pragma unroll
    for (int m2 = 1; m2 < 64; m2 <<= 1) {
        am += __shfl_xor(am, m2); al += __shfl_xor(al, m2); ac += __shfl_xor(ac, m2);
    }
    __shared__ float s[3][4];
    if (lane == 0) { s[0][wave] = am; s[1][wave] = al; s[2][wave] = ac; }
    __syncthreads();
    if (tid == 0) {
        float* a = &lossacc[(blockIdx.x & 7) * 3];
        atomicAdd(&a[0], s[0][0]+s[0][1]+s[0][2]+s[0][3]);
        atomicAdd(&a[1], s[1][0]+s[1][1]+s[1][2]+s[1][3]);
        atomicAdd(&a[2], s[2][0]+s[2][1]+s[2][2]+s[2][3]);
    }
}

__global__ void finloss_kernel(const float* __restrict__ lacc, float* __restrict__ out) {
    float m = 0.f, l = 0.f, c = 0.f;
    #pragma unroll
    for (int sl = 0; sl < 8; ++sl) { m += lacc[sl*3+0]; l += lacc[sl*3+1]; c += lacc[sl*3+2]; }
    out[0] = (l + c) / (m + 1e-8f);
}

extern "C" void kernel_launch(void* const* d_in, const int* in_sizes, int n_in,
                              void* d_out, int out_size, void* d_ws, size_t ws_size,
                              hipStream_t stream) {
    const float* coord  = (const float*)d_in[0];
    const float* feat   = (const float*)d_in[1];
    const float* bottom = (const float*)d_in[2];
    const float* stemv  = (const float*)d_in[3];
    const int*   inst   = (const int*)d_in[4];
    const float* w1     = (const float*)d_in[5];
    const float* b1     = (const float*)d_in[6];
    const float* gamma  = (const float*)d_in[7];
    const float* beta   = (const float*)d_in[8];
    const float* w2     = (const float*)d_in[9];
    const float* b2     = (const float*)d_in[10];
    const float* wseg   = (const float*)d_in[11];
    const float* bseg   = (const float*)d_in[12];

    float* out    = (float*)d_out;
    float* logits = out;
    float* bias   = out + (size_t)NPTS * NCLS;
    float* lossp  = out + (size_t)NPTS * 23;

    float* ws    = (float*)d_ws;
    float* stats = ws;                    // [32][128]
    float* lacc  = ws + 4096;             // [8][3]
    float* ab    = ws + 4160;             // [128]
    short* w1f   = (short*)(ws + 8192);   // 4096 bf16
    short* wsegf = (short*)(ws + 10240);  // 2048 bf16

    init_prep_kernel<<<12, 256, 0, stream>>>(w1, wseg, ws);
    pass1_kernel<<<GRID, 256, 0, stream>>>(feat, b1, bseg, w1f, wsegf, logits, stats);
    finstats_kernel<<<1, 64, 0, stream>>>(stats, gamma, beta, ab);
    pass2_kernel<<<GRID, 256, 0, stream>>>(feat, b1, w1f, ab, w2, b2,
                                           coord, bottom, stemv, inst, bias, lacc);
    finloss_kernel<<<1, 1, 0, stream>>>(lacc, lossp);
}

// Round 16
// 164.093 us; speedup vs baseline: 1.3330x; 1.0776x over previous
//
#include <hip/hip_runtime.h>
#include <hip/hip_bf16.h>

#define NPTS 1048576
#define NCLS 20
#define TILES 8
#define GRID  2048

using bf16x8 = __attribute__((ext_vector_type(8))) short;
using f32x4  = __attribute__((ext_vector_type(4))) float;

__device__ inline short bft(float f) {
    unsigned u = __builtin_bit_cast(unsigned, f);
    u += 0x8000u;                  // round-to-nearest-ish (no NaN/inf in data)
    return (short)(u >> 16);
}

__device__ inline bf16x8 cvt8(float4 a, float4 b) {
    bf16x8 r;
    r[0]=bft(a.x); r[1]=bft(a.y); r[2]=bft(a.z); r[3]=bft(a.w);
    r[4]=bft(b.x); r[5]=bft(b.y); r[6]=bft(b.z); r[7]=bft(b.w);
    return r;
}

// ws layout (float offsets):
//   [0,4096)    stats: 32 slices x (sum[64] | sumsq[64])
//   [4096,4120) loss acc: 8 slices x 3
//   [4160,4288) ab: scale[64] | shift[64]
//   [8192,10240)  w1f   (4096 shorts)
//   [10240,11264) wsegf (2048 shorts)

// ---- init + prep (12 blocks): zero accumulators, build MFMA B-fragment bf16 layouts
// frag layout: [cb][ks][lane][j] ; value = W[k = ks*32 + (lane>>4)*8 + j][c = cb*16 + (lane&15)]
__global__ void init_prep_kernel(const float* __restrict__ w1, const float* __restrict__ wseg,
                                 float* __restrict__ ws) {
    int b = blockIdx.x, t = threadIdx.x;
    short* w1f   = (short*)(ws + 8192);
    short* wsegf = (short*)(ws + 10240);
    if (b == 0) for (int i = t; i < 4288; i += 256) ws[i] = 0.f;
    if (b < 8) {                        // w1: 512 groups, 64 per block
        if (t < 64) {
            int g = b*64 + t;
            int lane = g & 63, ksb = g >> 6;
            int cb = ksb >> 1, ks = ksb & 1;
            int c = cb*16 + (lane & 15);
            int kb = ks*32 + (lane >> 4)*8;
            for (int j = 0; j < 8; ++j) w1f[g*8+j] = bft(w1[(kb+j)*64 + c]);
        }
    } else {                            // wseg: 256 groups, 64 per block
        if (t < 64) {
            int g = (b-8)*64 + t;
            int lane = g & 63, ksb = g >> 6;
            int cb = ksb >> 1, ks = ksb & 1;
            int c = cb*16 + (lane & 15);
            int kb = ks*32 + (lane >> 4)*8;
            for (int j = 0; j < 8; ++j)
                wsegf[g*8+j] = (c < NCLS) ? bft(wseg[(kb+j)*NCLS + c]) : (short)0;
        }
    }
}

// ---- pass1: h = feat@w1+b1 -> per-channel sum/sumsq; logits = feat@wseg+bseg
//      logits staged in LDS per wave -> fully-coalesced full-line NT f32x4 stores
__global__ __launch_bounds__(256) void pass1_kernel(
    const float* __restrict__ feat, const float* __restrict__ b1, const float* __restrict__ bseg,
    const short* __restrict__ w1f, const short* __restrict__ wsegf,
    float* __restrict__ out_logits, float* __restrict__ stats) {

    const int tid  = threadIdx.x;
    const int wave = tid >> 6;
    const int lane = tid & 63;
    const int l15  = lane & 15;
    const int lk   = lane >> 4;

    __shared__ float lgl[4][320];   // per-wave logits tile: 16 points x 20 ch

    bf16x8 w1frag[4][2];
    #pragma unroll
    for (int cb = 0; cb < 4; ++cb)
        #pragma unroll
        for (int ks = 0; ks < 2; ++ks)
            w1frag[cb][ks] = *(const bf16x8*)&w1f[((cb*2+ks)*64 + lane)*8];
    bf16x8 wsfrag[2][2];
    #pragma unroll
    for (int cb = 0; cb < 2; ++cb)
        #pragma unroll
        for (int ks = 0; ks < 2; ++ks)
            wsfrag[cb][ks] = *(const bf16x8*)&wsegf[((cb*2+ks)*64 + lane)*8];

    float b1v[4];
    #pragma unroll
    for (int cb = 0; cb < 4; ++cb) b1v[cb] = b1[cb*16 + l15];
    float bsegv[2];
    #pragma unroll
    for (int cb = 0; cb < 2; ++cb) { int c = cb*16+l15; bsegv[cb] = (c < NCLS) ? bseg[c] : 0.f; }

    float ssum[4] = {0,0,0,0}, ssq[4] = {0,0,0,0};

    auto do_tile = [&](float4 q0, float4 q1, float4 q2, float4 q3, int tt) {
        bf16x8 a0 = cvt8(q0, q1);
        bf16x8 a1 = cvt8(q2, q3);
        const int p0 = (blockIdx.x * TILES + tt) * 64 + wave * 16;

        f32x4 acc[4];
        #pragma unroll
        for (int cb = 0; cb < 4; ++cb) { acc[cb][0]=b1v[cb]; acc[cb][1]=b1v[cb]; acc[cb][2]=b1v[cb]; acc[cb][3]=b1v[cb]; }
        #pragma unroll
        for (int cb = 0; cb < 4; ++cb) {
            acc[cb] = __builtin_amdgcn_mfma_f32_16x16x32_bf16(a0, w1frag[cb][0], acc[cb], 0, 0, 0);
            acc[cb] = __builtin_amdgcn_mfma_f32_16x16x32_bf16(a1, w1frag[cb][1], acc[cb], 0, 0, 0);
        }
        #pragma unroll
        for (int cb = 0; cb < 4; ++cb)
            #pragma unroll
            for (int i = 0; i < 4; ++i) { float h = acc[cb][i]; ssum[cb] += h; ssq[cb] += h*h; }

        f32x4 lacc[2];
        #pragma unroll
        for (int cb = 0; cb < 2; ++cb) { lacc[cb][0]=0; lacc[cb][1]=0; lacc[cb][2]=0; lacc[cb][3]=0; }
        #pragma unroll
        for (int cb = 0; cb < 2; ++cb) {
            lacc[cb] = __builtin_amdgcn_mfma_f32_16x16x32_bf16(a0, wsfrag[cb][0], lacc[cb], 0, 0, 0);
            lacc[cb] = __builtin_amdgcn_mfma_f32_16x16x32_bf16(a1, wsfrag[cb][1], lacc[cb], 0, 0, 0);
        }
        // stage logits tile in this wave's LDS region (wave-synchronous, no barrier)
        #pragma unroll
        for (int i = 0; i < 4; ++i)
            lgl[wave][(lk*4+i)*NCLS + l15] = lacc[0][i] + bsegv[0];
        if (l15 < 4) {
            #pragma unroll
            for (int i = 0; i < 4; ++i)
                lgl[wave][(lk*4+i)*NCLS + 16 + l15] = lacc[1][i] + bsegv[1];
        }
        // write back: 320 floats = 5120 B = 10 full 128B lines, f32x4-coalesced NT
        float* gbase = out_logits + (size_t)p0 * NCLS;
        f32x4 v0 = *(const f32x4*)&lgl[wave][lane*4];
        __builtin_nontemporal_store(v0, (f32x4*)(gbase + lane*4));
        if (lane < 16) {
            f32x4 v1 = *(const f32x4*)&lgl[wave][256 + lane*4];
            __builtin_nontemporal_store(v1, (f32x4*)(gbase + 256 + lane*4));
        }
    };

    const float* src = feat + ((size_t)blockIdx.x * TILES * 64 + wave*16 + l15) * 64 + lk*8;
    float4 r0 = *(const float4*)src,          r1 = *(const float4*)(src + 4);
    float4 r2 = *(const float4*)(src + 32),   r3 = *(const float4*)(src + 36);
    float4 r4 = *(const float4*)(src + 4096), r5 = *(const float4*)(src + 4100);
    float4 r6 = *(const float4*)(src + 4128), r7 = *(const float4*)(src + 4132);

    for (int p = 0; p < TILES/2; ++p) {
        float4 n0=r0,n1=r1,n2=r2,n3=r3,n4=r4,n5=r5,n6=r6,n7=r7;
        if (p + 1 < TILES/2) {
            const float* sn = src + (size_t)(2*p + 2) * 4096;
            n0 = *(const float4*)sn;          n1 = *(const float4*)(sn + 4);
            n2 = *(const float4*)(sn + 32);   n3 = *(const float4*)(sn + 36);
            n4 = *(const float4*)(sn + 4096); n5 = *(const float4*)(sn + 4100);
            n6 = *(const float4*)(sn + 4128); n7 = *(const float4*)(sn + 4132);
        }
        do_tile(r0, r1, r2, r3, 2*p);
        do_tile(r4, r5, r6, r7, 2*p + 1);
        r0=n0; r1=n1; r2=n2; r3=n3; r4=n4; r5=n5; r6=n6; r7=n7;
    }

    #pragma unroll
    for (int cb = 0; cb < 4; ++cb) {
        ssum[cb] += __shfl_xor(ssum[cb], 16); ssum[cb] += __shfl_xor(ssum[cb], 32);
        ssq[cb]  += __shfl_xor(ssq[cb], 16);  ssq[cb]  += __shfl_xor(ssq[cb], 32);
    }
    __shared__ float red[4][128];
    if (lk == 0) {
        #pragma unroll
        for (int cb = 0; cb < 4; ++cb) {
            red[wave][cb*16 + l15]      = ssum[cb];
            red[wave][64 + cb*16 + l15] = ssq[cb];
        }
    }
    __syncthreads();
    if (tid < 128) {
        float v = red[0][tid] + red[1][tid] + red[2][tid] + red[3][tid];
        atomicAdd(&stats[(blockIdx.x & 31) * 128 + tid], v);
    }
}

// ---- finalize BN stats -> per-channel scale/shift
__global__ void finstats_kernel(const float* __restrict__ stats, const float* __restrict__ gamma,
                                const float* __restrict__ beta, float* __restrict__ ab) {
    int c = threadIdx.x;  // 64
    float s = 0.f, q = 0.f;
    #pragma unroll
    for (int sl = 0; sl < 32; ++sl) { s += stats[sl*128 + c]; q += stats[sl*128 + 64 + c]; }
    float mu  = s * (1.0f / NPTS);
    float var = q * (1.0f / NPTS) - mu * mu;
    float a = gamma[c] * rsqrtf(var + 1e-3f);
    ab[c] = a;
    ab[64 + c] = beta[c] - mu * a;
}

#define SEL4(v0,v1,v2,v3) (l15==0 ? (v0) : (l15==1 ? (v1) : (l15==2 ? (v2) : (v3))))
#define SEL3(v0,v1,v2)    (l15==0 ? (v0) : (l15==1 ? (v1) : (v2)))

// ---- pass2 (+fused loss): recompute h, BN+ReLU, bias_pred = hn@w2 + b2; loss terms per point
__global__ __launch_bounds__(256) void pass2_kernel(
    const float* __restrict__ feat, const float* __restrict__ b1,
    const short* __restrict__ w1f, const float* __restrict__ ab,
    const float* __restrict__ w2, const float* __restrict__ b2,
    const float* __restrict__ coord, const float* __restrict__ bottom,
    const float* __restrict__ stemv, const int* __restrict__ inst,
    float* __restrict__ out_bias, float* __restrict__ lossacc) {

    const int tid  = threadIdx.x;
    const int wave = tid >> 6;
    const int lane = tid & 63;
    const int l15  = lane & 15;
    const int lk   = lane >> 4;

    bf16x8 w1frag[4][2];
    #pragma unroll
    for (int cb = 0; cb < 4; ++cb)
        #pragma unroll
        for (int ks = 0; ks < 2; ++ks)
            w1frag[cb][ks] = *(const bf16x8*)&w1f[((cb*2+ks)*64 + lane)*8];

    float b1v[4], av[4], bsv[4], w2v[4][3];
    #pragma unroll
    for (int cb = 0; cb < 4; ++cb) {
        int c = cb*16 + l15;
        b1v[cb] = b1[c];
        av[cb]  = ab[c];
        bsv[cb] = ab[64 + c];
        #pragma unroll
        for (int j = 0; j < 3; ++j) w2v[cb][j] = w2[c*3 + j];
    }
    float b2v = (l15 < 3) ? b2[l15] : 0.f;
    float b2x = b2[0], b2y = b2[1], b2z = b2[2];

    float am = 0.f, al = 0.f, ac = 0.f;   // loss accumulators

    auto do_tile = [&](float4 q0, float4 q1, float4 q2, float4 q3, int tt) {
        bf16x8 a0 = cvt8(q0, q1);
        bf16x8 a1 = cvt8(q2, q3);
        const int p0 = (blockIdx.x * TILES + tt) * 64 + wave * 16;

        f32x4 acc[4];
        #pragma unroll
        for (int cb = 0; cb < 4; ++cb) { acc[cb][0]=b1v[cb]; acc[cb][1]=b1v[cb]; acc[cb][2]=b1v[cb]; acc[cb][3]=b1v[cb]; }
        #pragma unroll
        for (int cb = 0; cb < 4; ++cb) {
            acc[cb] = __builtin_amdgcn_mfma_f32_16x16x32_bf16(a0, w1frag[cb][0], acc[cb], 0, 0, 0);
            acc[cb] = __builtin_amdgcn_mfma_f32_16x16x32_bf16(a1, w1frag[cb][1], acc[cb], 0, 0, 0);
        }

        float pb[4][3];
        #pragma unroll
        for (int i = 0; i < 4; ++i) { pb[i][0]=0; pb[i][1]=0; pb[i][2]=0; }
        #pragma unroll
        for (int cb = 0; cb < 4; ++cb)
            #pragma unroll
            for (int i = 0; i < 4; ++i) {
                float hn = fmaxf(acc[cb][i] * av[cb] + bsv[cb], 0.f);
                #pragma unroll
                for (int j = 0; j < 3; ++j) pb[i][j] += hn * w2v[cb][j];
            }
        #pragma unroll
        for (int m = 1; m <= 8; m <<= 1)
            #pragma unroll
            for (int i = 0; i < 4; ++i) {
                pb[i][0] += __shfl_xor(pb[i][0], m);
                pb[i][1] += __shfl_xor(pb[i][1], m);
                pb[i][2] += __shfl_xor(pb[i][2], m);
            }
        // bias store: lane l15 in {0,1,2} writes component l15 of the 4 points (static selects)
        if (l15 < 3) {
            #pragma unroll
            for (int i = 0; i < 4; ++i) {
                float v = SEL3(pb[i][0], pb[i][1], pb[i][2]) + b2v;
                out_bias[(size_t)(p0 + lk*4 + i) * 3 + l15] = v;
            }
        }
        // fused loss: lane l15 in {0..3} owns point i = l15
        if (l15 < 4) {
            int p = p0 + lk*4 + l15;
            float px = SEL4(pb[0][0], pb[1][0], pb[2][0], pb[3][0]) + b2x;
            float py = SEL4(pb[0][1], pb[1][1], pb[2][1], pb[3][1]) + b2y;
            float pz = SEL4(pb[0][2], pb[1][2], pb[2][2], pb[3][2]) + b2z;
            float m  = (inst[p] != -1) ? 1.f : 0.f;
            float cx = coord[p*3+0],  cy = coord[p*3+1],  cz = coord[p*3+2];
            float bx = bottom[p*3+0], by = bottom[p*3+1], bz = bottom[p*3+2];
            float vx = stemv[p*3+0],  vy = stemv[p*3+1],  vz = stemv[p*3+2];
            float dx = cx - bx, dy = cy - by, dz = cz - bz;
            float proj = dx*vx + dy*vy + dz*vz;
            float gx = proj*vx - dx, gy = proj*vy - dy, gz = proj*vz - dz;
            float l1 = fabsf(px-gx) + fabsf(py-gy) + fabsf(pz-gz);
            float nb = sqrtf(px*px + py*py + pz*pz) + 1e-8f;
            float ng = sqrtf(gx*gx + gy*gy + gz*gz) + 1e-8f;
            float cs = -(px*gx + py*gy + pz*gz) / (nb * ng);
            am += m; al += l1 * m; ac += cs * m;
        }
    };

    const float* src = feat + ((size_t)blockIdx.x * TILES * 64 + wave*16 + l15) * 64 + lk*8;
    float4 r0 = *(const float4*)src,          r1 = *(const float4*)(src + 4);
    float4 r2 = *(const float4*)(src + 32),   r3 = *(const float4*)(src + 36);
    float4 r4 = *(const float4*)(src + 4096), r5 = *(const float4*)(src + 4100);
    float4 r6 = *(const float4*)(src + 4128), r7 = *(const float4*)(src + 4132);

    for (int p = 0; p < TILES/2; ++p) {
        float4 n0=r0,n1=r1,n2=r2,n3=r3,n4=r4,n5=r5,n6=r6,n7=r7;
        if (p + 1 < TILES/2) {
            const float* sn = src + (size_t)(2*p + 2) * 4096;
            n0 = *(const float4*)sn;          n1 = *(const float4*)(sn + 4);
            n2 = *(const float4*)(sn + 32);   n3 = *(const float4*)(sn + 36);
            n4 = *(const float4*)(sn + 4096); n5 = *(const float4*)(sn + 4100);
            n6 = *(const float4*)(sn + 4128); n7 = *(const float4*)(sn + 4132);
        }
        do_tile(r0, r1, r2, r3, 2*p);
        do_tile(r4, r5, r6, r7, 2*p + 1);
        r0=n0; r1=n1; r2=n2; r3=n3; r4=n4; r5=n5; r6=n6; r7=n7;
    }

    // block-level loss reduction
    #pragma unroll
    for (int m2 = 1; m2 < 64; m2 <<= 1) {
        am += __shfl_xor(am, m2); al += __shfl_xor(al, m2); ac += __shfl_xor(ac, m2);
    }
    __shared__ float s[3][4];
    if (lane == 0) { s[0][wave] = am; s[1][wave] = al; s[2][wave] = ac; }
    __syncthreads();
    if (tid == 0) {
        float* a = &lossacc[(blockIdx.x & 7) * 3];
        atomicAdd(&a[0], s[0][0]+s[0][1]+s[0][2]+s[0][3]);
        atomicAdd(&a[1], s[1][0]+s[1][1]+s[1][2]+s[1][3]);
        atomicAdd(&a[2], s[2][0]+s[2][1]+s[2][2]+s[2][3]);
    }
}

__global__ void finloss_kernel(const float* __restrict__ lacc, float* __restrict__ out) {
    float m = 0.f, l = 0.f, c = 0.f;
    #pragma unroll
    for (int sl = 0; sl < 8; ++sl) { m += lacc[sl*3+0]; l += lacc[sl*3+1]; c += lacc[sl*3+2]; }
    out[0] = (l + c) / (m + 1e-8f);
}

extern "C" void kernel_launch(void* const* d_in, const int* in_sizes, int n_in,
                              void* d_out, int out_size, void* d_ws, size_t ws_size,
                              hipStream_t stream) {
    const float* coord  = (const float*)d_in[0];
    const float* feat   = (const float*)d_in[1];
    const float* bottom = (const float*)d_in[2];
    const float* stemv  = (const float*)d_in[3];
    const int*   inst   = (const int*)d_in[4];
    const float* w1     = (const float*)d_in[5];
    const float* b1     = (const float*)d_in[6];
    const float* gamma  = (const float*)d_in[7];
    const float* beta   = (const float*)d_in[8];
    const float* w2     = (const float*)d_in[9];
    const float* b2     = (const float*)d_in[10];
    const float* wseg   = (const float*)d_in[11];
    const float* bseg   = (const float*)d_in[12];

    float* out    = (float*)d_out;
    float* logits = out;
    float* bias   = out + (size_t)NPTS * NCLS;
    float* lossp  = out + (size_t)NPTS * 23;

    float* ws    = (float*)d_ws;
    float* stats = ws;                    // [32][128]
    float* lacc  = ws + 4096;             // [8][3]
    float* ab    = ws + 4160;             // [128]
    short* w1f   = (short*)(ws + 8192);   // 4096 bf16
    short* wsegf = (short*)(ws + 10240);  // 2048 bf16

    init_prep_kernel<<<12, 256, 0, stream>>>(w1, wseg, ws);
    pass1_kernel<<<GRID, 256, 0, stream>>>(feat, b1, bseg, w1f, wsegf, logits, stats);
    finstats_kernel<<<1, 64, 0, stream>>>(stats, gamma, beta, ab);
    pass2_kernel<<<GRID, 256, 0, stream>>>(feat, b1, w1f, ab, w2, b2,
                                           coord, bottom, stemv, inst, bias, lacc);
    finloss_kernel<<<1, 1, 0, stream>>>(lacc, lossp);
}